// Round 13
// baseline (254.914 us; speedup 1.0000x reference)
//
#include <hip/hip_runtime.h>
#include <math.h>

#define Bn 8
#define NCn 384
#define Hn 32
#define Wn 32
#define Gn 6
#define GCn 64
#define HEADSn 12
#define Dn 32
#define HKn 15
#define WKn 15
#define NSn 225
#define NQn 1024
#define NKVn 900
#define VKB 30        // V key-blocks: 30*32 = 960 keys (900 real, rest zero-filled)
#define KBq 12        // K/32 blocks for K=384
#define CEXP 0.25503486f   // (1/sqrt(32)) * log2(e) — folded into Q at projection

typedef __attribute__((ext_vector_type(8))) short short8;
typedef __attribute__((ext_vector_type(4))) float floatx4;

__device__ __forceinline__ float gelu_f(float x) {
    return 0.5f * x * (1.0f + erff(x * 0.70710678118654752f));
}

__device__ __forceinline__ ushort f2bf(float x) {
    unsigned u = __float_as_uint(x);
    u = (u + 0x7FFF + ((u >> 16) & 1)) >> 16;   // RNE
    return (ushort)u;
}

// cheap round-half-up bf16 pack (hot P path; <= 1 ulp vs RNE)
__device__ __forceinline__ ushort f2bf_fast(float x) {
    return (ushort)((__float_as_uint(x) + 0x8000u) >> 16);
}

// P-tile LDS swizzle (R13): [16 rows][64 cols] ushort, granule(8 ushort)
// index XORed with quad(row)<<1 -> writes spread all 32 banks (was 8-way
// at stride 80: quad*160 dwords ≡ 0 mod 32), reads stay 16B-aligned b128.
__device__ __forceinline__ int pidx(int row, int col) {
    int g = col >> 3;
    int gs = g ^ (((row >> 2) & 3) << 1);
    return (row << 6) + (gs << 3) + (col & 7);
}

// ---------------------------------------------------------------------------
// k_prep: fused preprocessing, one launch, 1024 blocks.
//  id [0,768):    transpose4 -> dataT (bg, kb=8, n, 32) bf16  [R14 K-outer]
//  id [768,896):  transposeQ -> qXT (b, kb, n, 32) bf16  [R12 K-outer]
//  id [896,1024): cvtw grid-stride -> wb (all weights (kb, m, 32) blocks)
// R16: transpose phases vectorized 4x (float4 loads / ushort4 stores).
// ---------------------------------------------------------------------------
__global__ __launch_bounds__(256) void k_prep(
    const float* __restrict__ xr1, const float* __restrict__ xr2,
    const float* __restrict__ xx1, const float* __restrict__ xx2,
    const float* __restrict__ query,
    const float* __restrict__ w1, const float* __restrict__ qw,
    const float* __restrict__ kw, const float* __restrict__ vw,
    const float* __restrict__ ow,
    ushort* __restrict__ dataT, ushort* __restrict__ qXT,
    ushort* __restrict__ wb)
{
    __shared__ float lds[64 * 65];
    const int id = blockIdx.x;
    const int tid = threadIdx.x;

    if (id < 768) {
        const int bg = id % 48, hwt = id / 48;
        const int b = bg / Gn, g = bg % Gn;
        for (int kc = 0; kc < 4; ++kc) {
            for (int idx = tid; idx < 1024; idx += 256) {
                int cl = idx >> 4, hwl4 = (idx & 15) * 4;
                int gch = g * 256 + kc * 64 + cl;
                int m = gch / NCn, cm = gch % NCn;
                const float* img = (m == 0) ? xr1 : (m == 1) ? xr2 : (m == 2) ? xx1 : xx2;
                float4 v = *(const float4*)&img[(b * NCn + cm) * NQn + hwt * 64 + hwl4];
                lds[cl * 65 + hwl4 + 0] = v.x;
                lds[cl * 65 + hwl4 + 1] = v.y;
                lds[cl * 65 + hwl4 + 2] = v.z;
                lds[cl * 65 + hwl4 + 3] = v.w;
            }
            __syncthreads();
            for (int idx = tid; idx < 1024; idx += 256) {
                int hwl = idx >> 4, cl4 = (idx & 15) * 4;
                int ch = kc * 64 + cl4, kb = ch >> 5, k32 = ch & 31;
                ushort4 pk;
                pk.x = f2bf(lds[(cl4 + 0) * 65 + hwl]);
                pk.y = f2bf(lds[(cl4 + 1) * 65 + hwl]);
                pk.z = f2bf(lds[(cl4 + 2) * 65 + hwl]);
                pk.w = f2bf(lds[(cl4 + 3) * 65 + hwl]);
                *(ushort4*)&dataT[((size_t)(bg * 8 + kb) * NQn + hwt * 64 + hwl) * 32 + k32] = pk;
            }
            __syncthreads();
        }
    } else if (id < 896) {
        const int j = id - 768;
        const int b = j & 7, hwt = j >> 3;
        for (int kc = 0; kc < 6; ++kc) {
            for (int idx = tid; idx < 1024; idx += 256) {
                int cl = idx >> 4, hwl4 = (idx & 15) * 4;
                float4 v = *(const float4*)&query[((size_t)b * NCn + kc * 64 + cl) * NQn +
                                                  hwt * 64 + hwl4];
                lds[cl * 65 + hwl4 + 0] = v.x;
                lds[cl * 65 + hwl4 + 1] = v.y;
                lds[cl * 65 + hwl4 + 2] = v.z;
                lds[cl * 65 + hwl4 + 3] = v.w;
            }
            __syncthreads();
            for (int idx = tid; idx < 1024; idx += 256) {
                int hwl = idx >> 4, cl4 = (idx & 15) * 4;
                int ch = kc * 64 + cl4, kb = ch >> 5, k32 = ch & 31;
                ushort4 pk;
                pk.x = f2bf(lds[(cl4 + 0) * 65 + hwl]);
                pk.y = f2bf(lds[(cl4 + 1) * 65 + hwl]);
                pk.z = f2bf(lds[(cl4 + 2) * 65 + hwl]);
                pk.w = f2bf(lds[(cl4 + 3) * 65 + hwl]);
                *(ushort4*)&qXT[((size_t)(b * KBq + kb) * NQn + hwt * 64 + hwl) * 32 + k32] = pk;
            }
            __syncthreads();
        }
    } else {
        const int j = id - 896;   // 0..127
        for (int i = j * 256 + tid; i < 606208; i += 128 * 256) {
            float v;
            if (i < 16384) {                                 // w1 (kb=8, m=64, 32)
                int kb = i >> 11, r = i & 2047;
                v = w1[(r >> 5) * 256 + kb * 32 + (r & 31)];
            } else if (i < 163840) {
                int t = i - 16384, kb = t / 12288, r = t % 12288;
                v = qw[(r >> 5) * NCn + kb * 32 + (r & 31)]; // (kb, m, 32)
            } else if (i < 311296) {
                int t = i - 163840, kb = t / 12288, r = t % 12288;
                v = kw[(r >> 5) * NCn + kb * 32 + (r & 31)];
            } else if (i < 458752) {
                int t = i - 311296, kb = t / 12288, r = t % 12288;
                v = vw[(r >> 5) * NCn + kb * 32 + (r & 31)];
            } else {                                         // ow (kb=12, m=384, 32)
                int t = i - 458752, kb = t / 12288, r = t % 12288;
                v = ow[(r >> 5) * NCn + kb * 32 + (r & 31)];
            }
            wb[i] = f2bf(v);
        }
    }
}

// ---------------------------------------------------------------------------
// k_g3q (R20): merged launch — both halves depend only on k_prep outputs.
//  id [0,768):    mode3 GEMM (R18 geometry: 32n tiles, unroll 4) -> t1T
//  id [768,1152): Q projection (R10 geometry: 64n tiles, unroll 2) -> qTb
// ---------------------------------------------------------------------------
__global__ __launch_bounds__(256) void k_g3q(
    const ushort* __restrict__ w1b, const ushort* __restrict__ dataT,
    const float* __restrict__ b1, float* __restrict__ t1T,
    const ushort* __restrict__ qwb, const ushort* __restrict__ qXT,
    const float* __restrict__ q_b, ushort* __restrict__ qTb)
{
    const int id = blockIdx.x;
    const int w = threadIdx.x >> 6, lane = threadIdx.x & 63;
    const int l16 = lane & 15, quad = lane >> 4;
    floatx4 zero = {0.0f, 0.0f, 0.0f, 0.0f};

    if (id < 768) {
        // ---- mode3: GELU GEMM -> t1T; nb=id&7, mb=(id>>3)&1, bg=id>>4 ----
        const int nb = id & 7, rest = id >> 3;
        const int mb = rest & 1, b = rest >> 1;     // b = bg 0..47
        const int m0 = mb * 32;
        const int n0 = nb * 128 + w * 32;

        floatx4 acc[2][2] = {{zero, zero}, {zero, zero}};
        const ushort* a0 = w1b + (size_t)(m0 + l16) * 32 + quad * 8;
        const ushort* bp = dataT + ((size_t)b * 8 * NQn + n0 + l16) * 32 + quad * 8;

        #pragma unroll 4
        for (int kb = 0; kb < 8; ++kb) {
            const ushort* ak = a0 + (size_t)kb * (64 * 32);
            const ushort* bk = bp + (size_t)kb * (NQn * 32);
            short8 af0 = *(const short8*)(ak);
            short8 af1 = *(const short8*)(ak + 16 * 32);
            short8 bf[2];
            #pragma unroll
            for (int t = 0; t < 2; ++t)
                bf[t] = *(const short8*)(bk + t * 16 * 32);
            #pragma unroll
            for (int t = 0; t < 2; ++t) {
                acc[0][t] = __builtin_amdgcn_mfma_f32_16x16x32_bf16(af0, bf[t], acc[0][t], 0, 0, 0);
                acc[1][t] = __builtin_amdgcn_mfma_f32_16x16x32_bf16(af1, bf[t], acc[1][t], 0, 0, 0);
            }
        }
        #pragma unroll
        for (int a = 0; a < 2; ++a) {
            const int mbase = m0 + a * 16 + quad * 4;     // 4-aligned
            float bb[4];
            #pragma unroll
            for (int r = 0; r < 4; ++r) bb[r] = b1[mbase + r];
            #pragma unroll
            for (int t = 0; t < 2; ++t) {
                int n = n0 + t * 16 + l16;
                float4 v;
                v.x = gelu_f(acc[a][t][0] + bb[0]);
                v.y = gelu_f(acc[a][t][1] + bb[1]);
                v.z = gelu_f(acc[a][t][2] + bb[2]);
                v.w = gelu_f(acc[a][t][3] + bb[3]);
                *(float4*)&t1T[(((size_t)b << 10) + n) * 64 + mbase] = v;
            }
        }
    } else {
        // ---- Q projection (R10 form): qid=id-768; nb=qid&3, mb, b ----
        const int qid = id - 768;
        const int nb = qid & 3, rest = qid >> 2;    // 0..95
        const int mb = rest % HEADSn, b = rest / HEADSn;  // b 0..7
        const int m0 = mb * 32;
        const int n0 = nb * 256 + w * 64;

        floatx4 acc[2][4] = {{zero, zero, zero, zero}, {zero, zero, zero, zero}};
        const ushort* a0 = qwb + (size_t)(m0 + l16) * 32 + quad * 8;
        const ushort* bp = qXT + ((size_t)b * KBq * NQn + n0 + l16) * 32 + quad * 8;

        #pragma unroll 2
        for (int kb = 0; kb < KBq; ++kb) {
            const ushort* ak = a0 + (size_t)kb * (NCn * 32);
            const ushort* bk = bp + (size_t)kb * (NQn * 32);
            short8 af0 = *(const short8*)(ak);
            short8 af1 = *(const short8*)(ak + 16 * 32);
            short8 bf[4];
            #pragma unroll
            for (int t = 0; t < 4; ++t)
                bf[t] = *(const short8*)(bk + t * 16 * 32);
            #pragma unroll
            for (int t = 0; t < 4; ++t) {
                acc[0][t] = __builtin_amdgcn_mfma_f32_16x16x32_bf16(af0, bf[t], acc[0][t], 0, 0, 0);
                acc[1][t] = __builtin_amdgcn_mfma_f32_16x16x32_bf16(af1, bf[t], acc[1][t], 0, 0, 0);
            }
        }
        #pragma unroll
        for (int a = 0; a < 2; ++a) {
            #pragma unroll
            for (int t2 = 0; t2 < 4; ++t2) {
                int n = n0 + t2 * 16 + l16;   // always < 1024
                ushort4 pk;
                pk.x = f2bf((acc[a][t2][0] + q_b[m0 + a * 16 + quad * 4 + 0]) * CEXP);
                pk.y = f2bf((acc[a][t2][1] + q_b[m0 + a * 16 + quad * 4 + 1]) * CEXP);
                pk.z = f2bf((acc[a][t2][2] + q_b[m0 + a * 16 + quad * 4 + 2]) * CEXP);
                pk.w = f2bf((acc[a][t2][3] + q_b[m0 + a * 16 + quad * 4 + 3]) * CEXP);
                *(ushort4*)&qTb[((size_t)(b * HEADSn + mb) * NQn + n) * 32 +
                                a * 16 + quad * 4] = pk;
            }
        }
    }
}

// ---------------------------------------------------------------------------
// k_offsets: depthwise 3x3 stride2 + GELU + 1x1 (64->2) + tanh -> pixel coords.
// Wave-per-sample: needs 10800 waves -> grid 2700 blocks x 4 waves.
// t1T is (bg, hw, c) fp32: each tap is a 256B lane-contiguous read.
// ---------------------------------------------------------------------------
__global__ __launch_bounds__(256) void k_offsets(
    const float* __restrict__ t1T, const float* __restrict__ w2,
    const float* __restrict__ b2, const float* __restrict__ w3,
    float* __restrict__ posb)
{
    const int wid  = blockIdx.x * 4 + (threadIdx.x >> 6);   // 0..10799
    const int lane = threadIdx.x & 63;
    const int bg = wid / NSn, s = wid % NSn;
    const int hk = s / WKn, wk = s % WKn;

    const float* tbase = t1T + ((size_t)bg << 10) * 64;
    const float* wp = w2 + lane * 9;
    float sv = b2[lane];
    #pragma unroll
    for (int i = 0; i < 3; ++i)
        #pragma unroll
        for (int j = 0; j < 3; ++j)
            sv += tbase[(size_t)(((hk * 2 + i) * Wn + wk * 2 + j) * 64 + lane)] * wp[i * 3 + j];
    float gv = gelu_f(sv);
    float ay = w3[lane] * gv;
    float ax = w3[64 + lane] * gv;
    #pragma unroll
    for (int off = 32; off > 0; off >>= 1) {
        ay += __shfl_xor(ay, off, 64);
        ax += __shfl_xor(ax, off, 64);
    }
    if (lane == 0) {
        float fy = tanhf(ay) * (2.0f / 14.0f);
        float fx = tanhf(ax) * (2.0f / 14.0f);
        float cy = (float)(hk * 2 + 1) * (2.0f / 31.0f) - 1.0f;
        float cx = (float)(wk * 2 + 1) * (2.0f / 31.0f) - 1.0f;
        float py = fminf(fmaxf(fy + cy, -1.0f), 1.0f);
        float px = fminf(fmaxf(fx + cx, -1.0f), 1.0f);
        posb[wid * 2 + 0] = (py + 1.0f) * 0.5f * 31.0f;
        posb[wid * 2 + 1] = (px + 1.0f) * 0.5f * 31.0f;
    }
}

// ---------------------------------------------------------------------------
// k_sample: bilinear gathers -> smpT (b, kb, n(pad 1024), 32) bf16 [R12 layout].
// Grid (192, 4): x = (b,g,m) flat, y = 57-sample chunk -> 768 blocks for TLP.
// Rows n in [900,1024) stay stale — kv masks those columns on store.
// ---------------------------------------------------------------------------
__global__ __launch_bounds__(256) void k_sample(
    const float* __restrict__ xr1, const float* __restrict__ xr2,
    const float* __restrict__ xx1, const float* __restrict__ xx2,
    const float* __restrict__ posb, ushort* __restrict__ smpT)
{
    const int b = blockIdx.x & 7;
    const int j = blockIdx.x >> 3;          // 0..23
    const int g = j % Gn, m = j / Gn;       // m 0..3
    const int bg = b * Gn + g;
    const int s0 = blockIdx.y * 57;
    const int ns = min(57, NSn - s0);       // 57,57,57,54
    const float* img = (m == 0) ? xr1 : (m == 1) ? xr2 : (m == 2) ? xx1 : xx2;

    for (int idx = threadIdx.x; idx < 64 * ns; idx += 256) {
        int c = idx & 63, s = s0 + (idx >> 6);
        float py = posb[(bg * NSn + s) * 2 + 0];
        float px = posb[(bg * NSn + s) * 2 + 1];
        float y0f = floorf(py), x0f = floorf(px);
        float wy = py - y0f, wx = px - x0f;
        int y0 = (int)y0f, x0 = (int)x0f;
        int y1 = min(y0 + 1, Hn - 1), x1 = min(x0 + 1, Wn - 1);
        const float* base = img + (b * NCn + g * GCn + c) * NQn;
        float v00 = base[y0 * Wn + x0], v01 = base[y0 * Wn + x1];
        float v10 = base[y1 * Wn + x0], v11 = base[y1 * Wn + x1];
        float v = v00 * (1.0f - wy) * (1.0f - wx) + v01 * (1.0f - wy) * wx
                + v10 * wy * (1.0f - wx) + v11 * wy * wx;
        int ch = g * GCn + c;                    // channel 0..383
        int kb = ch >> 5, k32 = ch & 31;
        int n = m * NSn + s;                     // 0..899
        smpT[((size_t)(b * KBq + kb) * NQn + n) * 32 + k32] = f2bf(v);
    }
}

// ---------------------------------------------------------------------------
// MFMA GEMM — R14 K-outer blocked operands (1KB contiguous wave loads).
// R18: nb=8, wave tile 32m x 32n, 768 blocks (3/CU). R17 unroll 4.
// Used for mode 0 only (mode3 lives in k_g3q).
// ---------------------------------------------------------------------------
__global__ __launch_bounds__(256) void k_gemm(
    const ushort* __restrict__ A, const ushort* __restrict__ XT,
    const float* __restrict__ bias, const float* __restrict__ resid,
    float* __restrict__ Yf,
    int K, int Npad, int N, int mode)
{
    const int nb = blockIdx.x, mb = blockIdx.y, b = blockIdx.z;
    const int w = threadIdx.x >> 6, lane = threadIdx.x & 63;
    const int l16 = lane & 15, quad = lane >> 4;
    const int m0 = mb * 32;
    const int n0 = nb * 128 + w * 32;
    const int KB = K >> 5;
    const int M = (mode == 0) ? NCn : 64;

    floatx4 zero = {0.0f, 0.0f, 0.0f, 0.0f};
    floatx4 acc[2][2] = {{zero, zero}, {zero, zero}};

    const ushort* a0 = A + (size_t)(m0 + l16) * 32 + quad * 8;
    const ushort* bp = XT + ((size_t)b * KB * Npad + n0 + l16) * 32 + quad * 8;

    #pragma unroll 4
    for (int kb = 0; kb < KB; ++kb) {
        const ushort* ak = a0 + (size_t)kb * (M * 32);
        const ushort* bk = bp + (size_t)kb * (Npad * 32);
        short8 af0 = *(const short8*)(ak);
        short8 af1 = *(const short8*)(ak + 16 * 32);
        short8 bf[2];
        #pragma unroll
        for (int t = 0; t < 2; ++t)
            bf[t] = *(const short8*)(bk + t * 16 * 32);
        #pragma unroll
        for (int t = 0; t < 2; ++t) {
            acc[0][t] = __builtin_amdgcn_mfma_f32_16x16x32_bf16(af0, bf[t], acc[0][t], 0, 0, 0);
            acc[1][t] = __builtin_amdgcn_mfma_f32_16x16x32_bf16(af1, bf[t], acc[1][t], 0, 0, 0);
        }
    }

    if (mode == 0) {
        #pragma unroll
        for (int a = 0; a < 2; ++a)
            #pragma unroll
            for (int r = 0; r < 4; ++r) {
                int m = m0 + a * 16 + quad * 4 + r;
                float bb = bias[m];
                #pragma unroll
                for (int t = 0; t < 2; ++t) {
                    int n = n0 + t * 16 + l16;
                    size_t o = ((size_t)b * NCn + m) * N + n;
                    Yf[o] = acc[a][t][r] + bb + resid[o];
                }
            }
    } else {
        #pragma unroll
        for (int a = 0; a < 2; ++a) {
            const int mbase = m0 + a * 16 + quad * 4;
            float bb[4];
            #pragma unroll
            for (int r = 0; r < 4; ++r) bb[r] = bias[mbase + r];
            #pragma unroll
            for (int t = 0; t < 2; ++t) {
                int n = n0 + t * 16 + l16;
                float4 v;
                v.x = gelu_f(acc[a][t][0] + bb[0]);
                v.y = gelu_f(acc[a][t][1] + bb[1]);
                v.z = gelu_f(acc[a][t][2] + bb[2]);
                v.w = gelu_f(acc[a][t][3] + bb[3]);
                *(float4*)&Yf[(((size_t)b << 10) + n) * 64 + mbase] = v;
            }
        }
    }
}

// ---------------------------------------------------------------------------
// k_kv: KV-only projection, R10 64-wide geometry. R21: unroll 2->4 — at 384
// blocks (1.5/CU) this launch is in the same latency-starved regime R9 fixed
// on k_gemm with unroll 4 (-5.7 µs measured); R12's split removed the Q-plane
// TLP, ILP must replace it. 12 % 4 == 0.
// ---------------------------------------------------------------------------
__global__ __launch_bounds__(256) void k_kv(
    const ushort* __restrict__ kwb, const ushort* __restrict__ vwb,
    const ushort* __restrict__ smpT,
    const float* __restrict__ k_b, const float* __restrict__ v_b,
    ushort* __restrict__ kTb, ushort* __restrict__ vTb)
{
    const int nb = blockIdx.x, mb = blockIdx.y, b = blockIdx.z;
    const int w = threadIdx.x >> 6, lane = threadIdx.x & 63;
    const int l16 = lane & 15, quad = lane >> 4;
    const int m0 = mb * 32;
    const int n0 = nb * 256 + w * 64;
    floatx4 zero = {0.0f, 0.0f, 0.0f, 0.0f};

    floatx4 acck[2][4] = {{zero, zero, zero, zero}, {zero, zero, zero, zero}};
    floatx4 accv[2][4] = {{zero, zero, zero, zero}, {zero, zero, zero, zero}};
    const ushort* ak0 = kwb + (size_t)(m0 + l16) * 32 + quad * 8;
    const ushort* av0 = vwb + (size_t)(m0 + l16) * 32 + quad * 8;
    const ushort* bp  = smpT + ((size_t)b * KBq * NQn + n0 + l16) * 32 + quad * 8;

    #pragma unroll 4
    for (int kb = 0; kb < KBq; ++kb) {
        const ushort* ak = ak0 + (size_t)kb * (NCn * 32);
        const ushort* av = av0 + (size_t)kb * (NCn * 32);
        const ushort* bk = bp + (size_t)kb * (NQn * 32);
        short8 afk0 = *(const short8*)(ak);
        short8 afk1 = *(const short8*)(ak + 16 * 32);
        short8 afv0 = *(const short8*)(av);
        short8 afv1 = *(const short8*)(av + 16 * 32);
        short8 bf[4];
        #pragma unroll
        for (int t = 0; t < 4; ++t)
            bf[t] = *(const short8*)(bk + t * 16 * 32);
        #pragma unroll
        for (int t = 0; t < 4; ++t) {
            acck[0][t] = __builtin_amdgcn_mfma_f32_16x16x32_bf16(afk0, bf[t], acck[0][t], 0, 0, 0);
            acck[1][t] = __builtin_amdgcn_mfma_f32_16x16x32_bf16(afk1, bf[t], acck[1][t], 0, 0, 0);
            accv[0][t] = __builtin_amdgcn_mfma_f32_16x16x32_bf16(afv0, bf[t], accv[0][t], 0, 0, 0);
            accv[1][t] = __builtin_amdgcn_mfma_f32_16x16x32_bf16(afv1, bf[t], accv[1][t], 0, 0, 0);
        }
    }
    #pragma unroll
    for (int a = 0; a < 2; ++a) {
        #pragma unroll
        for (int t2 = 0; t2 < 4; ++t2) {
            int n = n0 + t2 * 16 + l16;
            if (n < NKVn) {
                ushort4 pk;
                pk.x = f2bf(acck[a][t2][0] + k_b[m0 + a * 16 + quad * 4 + 0]);
                pk.y = f2bf(acck[a][t2][1] + k_b[m0 + a * 16 + quad * 4 + 1]);
                pk.z = f2bf(acck[a][t2][2] + k_b[m0 + a * 16 + quad * 4 + 2]);
                pk.w = f2bf(acck[a][t2][3] + k_b[m0 + a * 16 + quad * 4 + 3]);
                *(ushort4*)&kTb[((size_t)(b * HEADSn + mb) * NKVn + n) * 32 +
                                a * 16 + quad * 4] = pk;
            }
        }
    }
    // V epilogue — R15 tiled layout (b, h=mb, n>>5, d, n&31); R16: n<960 guard
    #pragma unroll
    for (int a = 0; a < 2; ++a)
        #pragma unroll
        for (int r = 0; r < 4; ++r) {
            int d = a * 16 + quad * 4 + r;
            float bv = v_b[m0 + d];
            #pragma unroll
            for (int t2 = 0; t2 < 4; ++t2) {
                int n = n0 + t2 * 16 + l16;   // 0..1023
                if (n < VKB * 32)
                    vTb[(((size_t)(b * HEADSn + mb) * VKB + (n >> 5)) * 32 + d) * 32 +
                        (n & 31)] = (n < NKVn) ? f2bf(accv[a][t2][r] + bv) : (ushort)0;
            }
        }
}

// ---------------------------------------------------------------------------
// Flash attention, bf16 MFMA, 32 queries/wave, K/V register prefetch.
// 768 blocks 1-D: b = id%8, j = id/8: h = j%12, mt = j/12.
// R13: raw v_exp (scores pre-scaled in Q), XOR-swizzled P tile (16 KB).
// R15: V in (b,h,kb,d,32) tiles -> vf loads 1KB-contiguous; setprio on MFMA
// clusters (4 independent waves/block, no barriers — measured +4-7% regime).
// ---------------------------------------------------------------------------
__global__ __launch_bounds__(256) void k_attn_mfma(
    const ushort* __restrict__ qT, const ushort* __restrict__ kT,
    const ushort* __restrict__ vb, ushort* __restrict__ aoutT)
{
    __shared__ __align__(16) ushort p_lds[4 * 2 * 16 * 64];   // 16 KB
    const int b = blockIdx.x & 7;
    const int j = blockIdx.x >> 3;          // 0..95
    const int h = j % HEADSn, mt = j / HEADSn;   // mt 0..7
    const int bh = b * HEADSn + h;
    const int tid = threadIdx.x;
    const int w = tid >> 6, lane = tid & 63;
    const int l16 = lane & 15, quad = lane >> 4;

    ushort* p_w[2] = { p_lds + (w * 2 + 0) * (16 * 64),
                       p_lds + (w * 2 + 1) * (16 * 64) };

    const int q0 = mt * 128 + w * 32;
    short8 qf[2];
    qf[0] = *(const short8*)(qT + (size_t)((bh * NQn + q0 + l16) * 32 + quad * 8));
    qf[1] = *(const short8*)(qT + (size_t)((bh * NQn + q0 + 16 + l16) * 32 + quad * 8));

    const ushort* kbase = kT + (size_t)bh * NKVn * 32;
    const ushort* vbase = vb + (size_t)bh * (VKB * 1024);   // 32d x 32k tiles

    floatx4 zero = {0.0f, 0.0f, 0.0f, 0.0f};
    floatx4 oacc[2][2] = {{zero, zero}, {zero, zero}};
    float lrun[2][4] = {};

    short8 kf[4];
    #pragma unroll
    for (int t = 0; t < 4; ++t)
        kf[t] = *(const short8*)(kbase + (size_t)((t * 16 + l16) * 32 + quad * 8));

    for (int nc = 0; nc < 15; ++nc) {
        const int n0 = nc * 64;
        short8 vf[2][2];
        #pragma unroll
        for (int kc = 0; kc < 2; ++kc)
            #pragma unroll
            for (int nt2 = 0; nt2 < 2; ++nt2)
                vf[kc][nt2] = *(const short8*)(vbase +
                    (size_t)(((nc * 2 + kc) * 32 + nt2 * 16 + l16) * 32 + quad * 8));

        floatx4 sf[2][4];
        __builtin_amdgcn_s_setprio(1);
        #pragma unroll
        for (int a = 0; a < 2; ++a)
            #pragma unroll
            for (int t = 0; t < 4; ++t)
                sf[a][t] = __builtin_amdgcn_mfma_f32_16x16x32_bf16(qf[a], kf[t], zero, 0, 0, 0);
        __builtin_amdgcn_s_setprio(0);

        if (nc < 14) {
            #pragma unroll
            for (int t = 0; t < 4; ++t)
                kf[t] = *(const short8*)(kbase +
                    (size_t)((n0 + 64 + t * 16 + l16) * 32 + quad * 8));
        }

        if (n0 + 64 <= NKVn) {
            #pragma unroll
            for (int a = 0; a < 2; ++a)
                #pragma unroll
                for (int t = 0; t < 4; ++t)
                    #pragma unroll
                    for (int r = 0; r < 4; ++r) {
                        float p = __builtin_amdgcn_exp2f(sf[a][t][r]);
                        lrun[a][r] += p;
                        p_w[a][pidx(quad * 4 + r, t * 16 + l16)] = f2bf_fast(p);
                    }
        } else {
            const int limit = NKVn - n0;
            #pragma unroll
            for (int a = 0; a < 2; ++a)
                #pragma unroll
                for (int t = 0; t < 4; ++t) {
                    const int col = t * 16 + l16;
                    #pragma unroll
                    for (int r = 0; r < 4; ++r) {
                        float p = (col < limit) ? __builtin_amdgcn_exp2f(sf[a][t][r]) : 0.0f;
                        lrun[a][r] += p;
                        p_w[a][pidx(quad * 4 + r, col)] = f2bf_fast(p);
                    }
                }
        }

        __builtin_amdgcn_s_setprio(1);
        #pragma unroll
        for (int a = 0; a < 2; ++a)
            #pragma unroll
            for (int kc = 0; kc < 2; ++kc) {
                const short8 pf = *(const short8*)(p_w[a] + pidx(l16, kc * 32 + quad * 8));
                #pragma unroll
                for (int nt2 = 0; nt2 < 2; ++nt2)
                    oacc[a][nt2] = __builtin_amdgcn_mfma_f32_16x16x32_bf16(
                        pf, vf[kc][nt2], oacc[a][nt2], 0, 0, 0);
            }
        __builtin_amdgcn_s_setprio(0);
    }

    #pragma unroll
    for (int a = 0; a < 2; ++a)
        #pragma unroll
        for (int r = 0; r < 4; ++r) {
            float l = lrun[a][r];
            l += __shfl_xor(l, 1, 64);
            l += __shfl_xor(l, 2, 64);
            l += __shfl_xor(l, 4, 64);
            l += __shfl_xor(l, 8, 64);
            lrun[a][r] = 1.0f / l;
        }

    #pragma unroll
    for (int a = 0; a < 2; ++a)
        #pragma unroll
        for (int nt2 = 0; nt2 < 2; ++nt2)
            #pragma unroll
            for (int r = 0; r < 4; ++r) {
                int m = q0 + a * 16 + quad * 4 + r;
                aoutT[((size_t)(b * HEADSn + h) * NQn + m) * 32 + nt2 * 16 + l16] =
                    f2bf(oacc[a][nt2][r] * lrun[a][r]);
            }
}

// ---------------------------------------------------------------------------
extern "C" void kernel_launch(void* const* d_in, const int* in_sizes, int n_in,
                              void* d_out, int out_size, void* d_ws, size_t ws_size,
                              hipStream_t stream) {
    const float* query = (const float*)d_in[0];
    const float* xr1   = (const float*)d_in[1];
    const float* xr2   = (const float*)d_in[2];
    const float* xx1   = (const float*)d_in[3];
    const float* xx2   = (const float*)d_in[4];
    const float* w1    = (const float*)d_in[5];
    const float* b1    = (const float*)d_in[6];
    const float* w2    = (const float*)d_in[7];
    const float* b2    = (const float*)d_in[8];
    const float* w3    = (const float*)d_in[9];
    const float* q_w   = (const float*)d_in[10];
    const float* q_b   = (const float*)d_in[11];
    const float* k_w   = (const float*)d_in[12];
    const float* k_b   = (const float*)d_in[13];
    const float* v_w   = (const float*)d_in[14];
    const float* v_b   = (const float*)d_in[15];
    const float* o_w   = (const float*)d_in[16];
    const float* o_b   = (const float*)d_in[17];
    float* out = (float*)d_out;

    // ---- workspace layout (float units), with liveness overlap ----
    float* ws = (float*)d_ws;
    ushort* dataT = (ushort*)ws;                   // 48*8*1024*32 u = 6,291,456 f
    ushort* qTb   = (ushort*)(ws + 1572864);       // 8*12*1024*32 u (dataT dead by attn) ✓
    ushort* aoutT = (ushort*)(ws + 3145728);       // 8*12*1024*32 u
    float*  t1T   = ws + 6291456;                  // 48*1024*64 fp32 = 3,145,728 f
    ushort* kTb   = (ushort*)(ws + 6291456);       // overlays t1T (dead after k_offsets) ✓
    ushort* vTb   = (ushort*)(ws + 7673856);       // 8*12*30*1024 u (same 2,949,120 u)
    float*  posb  = ws + 9437184;                  // 21,600 f (gap before smpT)
    ushort* smpT  = (ushort*)(ws + 9458816);       // 8*12*1024*32 u = 1,572,864 f
    ushort* wb    = (ushort*)(ws + 11031680);      // 606,208 u
    ushort* w1b = wb;
    ushort* qwb = wb + 16384;
    ushort* kwb = wb + 163840;
    ushort* vwb = wb + 311296;
    ushort* owb = wb + 458752;
    ushort* qXT2 = wb + 606208;                    // 8*12*1024*32 u (own slot: k_prep
                                                   //  writes it concurrently with dataT)

    k_prep<<<dim3(1024), 256, 0, stream>>>(xr1, xr2, xx1, xx2, query,
                                           w1, q_w, k_w, v_w, o_w,
                                           dataT, qXT2, wb);
    k_g3q<<<dim3(1152), 256, 0, stream>>>(w1b, dataT, b1, t1T,
                                          qwb, qXT2, q_b, qTb);
    k_offsets<<<dim3(2700), 256, 0, stream>>>(t1T, w2, b2, w3, posb);
    k_sample<<<dim3(192, 4), 256, 0, stream>>>(xr1, xr2, xx1, xx2, posb, smpT);
    k_kv<<<dim3(4, 12, Bn), 256, 0, stream>>>(kwb, vwb, smpT, k_b, v_b, kTb, vTb);
    k_attn_mfma<<<dim3(768), 256, 0, stream>>>(qTb, kTb, vTb, aoutT);
    k_gemm<<<dim3(8, 12, Bn), 256, 0, stream>>>(owb, aoutT, o_b, query,
                                                out, NCn, NQn, NQn, 0);
}

// Round 14
// 248.522 us; speedup vs baseline: 1.0257x; 1.0257x over previous
//
#include <hip/hip_runtime.h>
#include <math.h>

#define Bn 8
#define NCn 384
#define Hn 32
#define Wn 32
#define Gn 6
#define GCn 64
#define HEADSn 12
#define Dn 32
#define HKn 15
#define WKn 15
#define NSn 225
#define NQn 1024
#define NKVn 900
#define VKB 30        // V key-blocks: 30*32 = 960 keys (900 real, rest zero-filled)
#define KBq 12        // K/32 blocks for K=384
#define CEXP 0.25503486f   // (1/sqrt(32)) * log2(e) — folded into Q at projection

typedef __attribute__((ext_vector_type(8))) short short8;
typedef __attribute__((ext_vector_type(4))) float floatx4;

__device__ __forceinline__ float gelu_f(float x) {
    return 0.5f * x * (1.0f + erff(x * 0.70710678118654752f));
}

__device__ __forceinline__ ushort f2bf(float x) {
    unsigned u = __float_as_uint(x);
    u = (u + 0x7FFF + ((u >> 16) & 1)) >> 16;   // RNE
    return (ushort)u;
}

// cheap round-half-up bf16 pack (hot P path; <= 1 ulp vs RNE)
__device__ __forceinline__ ushort f2bf_fast(float x) {
    return (ushort)((__float_as_uint(x) + 0x8000u) >> 16);
}

// P-tile LDS swizzle (R13): [16 rows][64 cols] ushort, granule(8 ushort)
// index XORed with quad(row)<<1 -> writes spread all 32 banks (was 8-way
// at stride 80: quad*160 dwords ≡ 0 mod 32), reads stay 16B-aligned b128.
__device__ __forceinline__ int pidx(int row, int col) {
    int g = col >> 3;
    int gs = g ^ (((row >> 2) & 3) << 1);
    return (row << 6) + (gs << 3) + (col & 7);
}

// ---------------------------------------------------------------------------
// k_prep: fused preprocessing, one launch, 1024 blocks.
//  id [0,768):    transpose4 -> dataT (bg, kb=8, n, 32) bf16  [R14 K-outer]
//  id [768,896):  transposeQ -> qXT (b, kb, n, 32) bf16  [R12 K-outer]
//  id [896,1024): cvtw grid-stride -> wb (all weights (kb, m, 32) blocks)
// R16: transpose phases vectorized 4x (float4 loads / ushort4 stores).
// ---------------------------------------------------------------------------
__global__ __launch_bounds__(256) void k_prep(
    const float* __restrict__ xr1, const float* __restrict__ xr2,
    const float* __restrict__ xx1, const float* __restrict__ xx2,
    const float* __restrict__ query,
    const float* __restrict__ w1, const float* __restrict__ qw,
    const float* __restrict__ kw, const float* __restrict__ vw,
    const float* __restrict__ ow,
    ushort* __restrict__ dataT, ushort* __restrict__ qXT,
    ushort* __restrict__ wb)
{
    __shared__ float lds[64 * 65];
    const int id = blockIdx.x;
    const int tid = threadIdx.x;

    if (id < 768) {
        const int bg = id % 48, hwt = id / 48;
        const int b = bg / Gn, g = bg % Gn;
        for (int kc = 0; kc < 4; ++kc) {
            for (int idx = tid; idx < 1024; idx += 256) {
                int cl = idx >> 4, hwl4 = (idx & 15) * 4;
                int gch = g * 256 + kc * 64 + cl;
                int m = gch / NCn, cm = gch % NCn;
                const float* img = (m == 0) ? xr1 : (m == 1) ? xr2 : (m == 2) ? xx1 : xx2;
                float4 v = *(const float4*)&img[(b * NCn + cm) * NQn + hwt * 64 + hwl4];
                lds[cl * 65 + hwl4 + 0] = v.x;
                lds[cl * 65 + hwl4 + 1] = v.y;
                lds[cl * 65 + hwl4 + 2] = v.z;
                lds[cl * 65 + hwl4 + 3] = v.w;
            }
            __syncthreads();
            for (int idx = tid; idx < 1024; idx += 256) {
                int hwl = idx >> 4, cl4 = (idx & 15) * 4;
                int ch = kc * 64 + cl4, kb = ch >> 5, k32 = ch & 31;
                ushort4 pk;
                pk.x = f2bf(lds[(cl4 + 0) * 65 + hwl]);
                pk.y = f2bf(lds[(cl4 + 1) * 65 + hwl]);
                pk.z = f2bf(lds[(cl4 + 2) * 65 + hwl]);
                pk.w = f2bf(lds[(cl4 + 3) * 65 + hwl]);
                *(ushort4*)&dataT[((size_t)(bg * 8 + kb) * NQn + hwt * 64 + hwl) * 32 + k32] = pk;
            }
            __syncthreads();
        }
    } else if (id < 896) {
        const int j = id - 768;
        const int b = j & 7, hwt = j >> 3;
        for (int kc = 0; kc < 6; ++kc) {
            for (int idx = tid; idx < 1024; idx += 256) {
                int cl = idx >> 4, hwl4 = (idx & 15) * 4;
                float4 v = *(const float4*)&query[((size_t)b * NCn + kc * 64 + cl) * NQn +
                                                  hwt * 64 + hwl4];
                lds[cl * 65 + hwl4 + 0] = v.x;
                lds[cl * 65 + hwl4 + 1] = v.y;
                lds[cl * 65 + hwl4 + 2] = v.z;
                lds[cl * 65 + hwl4 + 3] = v.w;
            }
            __syncthreads();
            for (int idx = tid; idx < 1024; idx += 256) {
                int hwl = idx >> 4, cl4 = (idx & 15) * 4;
                int ch = kc * 64 + cl4, kb = ch >> 5, k32 = ch & 31;
                ushort4 pk;
                pk.x = f2bf(lds[(cl4 + 0) * 65 + hwl]);
                pk.y = f2bf(lds[(cl4 + 1) * 65 + hwl]);
                pk.z = f2bf(lds[(cl4 + 2) * 65 + hwl]);
                pk.w = f2bf(lds[(cl4 + 3) * 65 + hwl]);
                *(ushort4*)&qXT[((size_t)(b * KBq + kb) * NQn + hwt * 64 + hwl) * 32 + k32] = pk;
            }
            __syncthreads();
        }
    } else {
        const int j = id - 896;   // 0..127
        for (int i = j * 256 + tid; i < 606208; i += 128 * 256) {
            float v;
            if (i < 16384) {                                 // w1 (kb=8, m=64, 32)
                int kb = i >> 11, r = i & 2047;
                v = w1[(r >> 5) * 256 + kb * 32 + (r & 31)];
            } else if (i < 163840) {
                int t = i - 16384, kb = t / 12288, r = t % 12288;
                v = qw[(r >> 5) * NCn + kb * 32 + (r & 31)]; // (kb, m, 32)
            } else if (i < 311296) {
                int t = i - 163840, kb = t / 12288, r = t % 12288;
                v = kw[(r >> 5) * NCn + kb * 32 + (r & 31)];
            } else if (i < 458752) {
                int t = i - 311296, kb = t / 12288, r = t % 12288;
                v = vw[(r >> 5) * NCn + kb * 32 + (r & 31)];
            } else {                                         // ow (kb=12, m=384, 32)
                int t = i - 458752, kb = t / 12288, r = t % 12288;
                v = ow[(r >> 5) * NCn + kb * 32 + (r & 31)];
            }
            wb[i] = f2bf(v);
        }
    }
}

// ---------------------------------------------------------------------------
// k_offsets: depthwise 3x3 stride2 + GELU + 1x1 (64->2) + tanh -> pixel coords.
// Wave-per-sample: needs 10800 waves -> grid 2700 blocks x 4 waves.
// t1T is (bg, hw, c) fp32: each tap is a 256B lane-contiguous read.
// ---------------------------------------------------------------------------
__global__ __launch_bounds__(256) void k_offsets(
    const float* __restrict__ t1T, const float* __restrict__ w2,
    const float* __restrict__ b2, const float* __restrict__ w3,
    float* __restrict__ posb)
{
    const int wid  = blockIdx.x * 4 + (threadIdx.x >> 6);   // 0..10799
    const int lane = threadIdx.x & 63;
    const int bg = wid / NSn, s = wid % NSn;
    const int hk = s / WKn, wk = s % WKn;

    const float* tbase = t1T + ((size_t)bg << 10) * 64;
    const float* wp = w2 + lane * 9;
    float sv = b2[lane];
    #pragma unroll
    for (int i = 0; i < 3; ++i)
        #pragma unroll
        for (int j = 0; j < 3; ++j)
            sv += tbase[(size_t)(((hk * 2 + i) * Wn + wk * 2 + j) * 64 + lane)] * wp[i * 3 + j];
    float gv = gelu_f(sv);
    float ay = w3[lane] * gv;
    float ax = w3[64 + lane] * gv;
    #pragma unroll
    for (int off = 32; off > 0; off >>= 1) {
        ay += __shfl_xor(ay, off, 64);
        ax += __shfl_xor(ax, off, 64);
    }
    if (lane == 0) {
        float fy = tanhf(ay) * (2.0f / 14.0f);
        float fx = tanhf(ax) * (2.0f / 14.0f);
        float cy = (float)(hk * 2 + 1) * (2.0f / 31.0f) - 1.0f;
        float cx = (float)(wk * 2 + 1) * (2.0f / 31.0f) - 1.0f;
        float py = fminf(fmaxf(fy + cy, -1.0f), 1.0f);
        float px = fminf(fmaxf(fx + cx, -1.0f), 1.0f);
        posb[wid * 2 + 0] = (py + 1.0f) * 0.5f * 31.0f;
        posb[wid * 2 + 1] = (px + 1.0f) * 0.5f * 31.0f;
    }
}

// ---------------------------------------------------------------------------
// k_sample: bilinear gathers -> smpT (b, kb, n(pad 1024), 32) bf16 [R12 layout].
// Grid (192, 4): x = (b,g,m) flat, y = 57-sample chunk -> 768 blocks for TLP.
// Rows n in [900,1024) stay stale — qkv masks those columns on store.
// ---------------------------------------------------------------------------
__global__ __launch_bounds__(256) void k_sample(
    const float* __restrict__ xr1, const float* __restrict__ xr2,
    const float* __restrict__ xx1, const float* __restrict__ xx2,
    const float* __restrict__ posb, ushort* __restrict__ smpT)
{
    const int b = blockIdx.x & 7;
    const int j = blockIdx.x >> 3;          // 0..23
    const int g = j % Gn, m = j / Gn;       // m 0..3
    const int bg = b * Gn + g;
    const int s0 = blockIdx.y * 57;
    const int ns = min(57, NSn - s0);       // 57,57,57,54
    const float* img = (m == 0) ? xr1 : (m == 1) ? xr2 : (m == 2) ? xx1 : xx2;

    for (int idx = threadIdx.x; idx < 64 * ns; idx += 256) {
        int c = idx & 63, s = s0 + (idx >> 6);
        float py = posb[(bg * NSn + s) * 2 + 0];
        float px = posb[(bg * NSn + s) * 2 + 1];
        float y0f = floorf(py), x0f = floorf(px);
        float wy = py - y0f, wx = px - x0f;
        int y0 = (int)y0f, x0 = (int)x0f;
        int y1 = min(y0 + 1, Hn - 1), x1 = min(x0 + 1, Wn - 1);
        const float* base = img + (b * NCn + g * GCn + c) * NQn;
        float v00 = base[y0 * Wn + x0], v01 = base[y0 * Wn + x1];
        float v10 = base[y1 * Wn + x0], v11 = base[y1 * Wn + x1];
        float v = v00 * (1.0f - wy) * (1.0f - wx) + v01 * (1.0f - wy) * wx
                + v10 * wy * (1.0f - wx) + v11 * wy * wx;
        int ch = g * GCn + c;                    // channel 0..383
        int kb = ch >> 5, k32 = ch & 31;
        int n = m * NSn + s;                     // 0..899
        smpT[((size_t)(b * KBq + kb) * NQn + n) * 32 + k32] = f2bf(v);
    }
}

// ---------------------------------------------------------------------------
// MFMA GEMM — R14 K-outer blocked operands (1KB contiguous wave loads).
// R18: nb split 4->8, wave tile 32m x 32n (was 32x64) — grids 384->768 blocks
// (1.5->3 blocks/CU). B-load instrs per output column UNCHANGED (2 frags/kb
// per 32 cols); only tiny L2-hot A frags re-loaded. Pure TLP win; acc regs
// halve. R17 unroll 4 kept.
// A in (kb, m, 32) (M=384 mode0 / 64 mode3); XT in (b, kb, n(pad Npad), 32).
// mode 0: fp32 (b,384,N) + resid;  mode 3: GELU -> t1T (bg, hw, c) fp32.
// ---------------------------------------------------------------------------
__global__ __launch_bounds__(256) void k_gemm(
    const ushort* __restrict__ A, const ushort* __restrict__ XT,
    const float* __restrict__ bias, const float* __restrict__ resid,
    float* __restrict__ Yf,
    int K, int Npad, int N, int mode)
{
    const int nb = blockIdx.x, mb = blockIdx.y, b = blockIdx.z;
    const int w = threadIdx.x >> 6, lane = threadIdx.x & 63;
    const int l16 = lane & 15, quad = lane >> 4;
    const int m0 = mb * 32;
    const int n0 = nb * 128 + w * 32;
    const int KB = K >> 5;
    const int M = (mode == 0) ? NCn : 64;

    floatx4 zero = {0.0f, 0.0f, 0.0f, 0.0f};
    floatx4 acc[2][2] = {{zero, zero}, {zero, zero}};

    const ushort* a0 = A + (size_t)(m0 + l16) * 32 + quad * 8;
    const ushort* bp = XT + ((size_t)b * KB * Npad + n0 + l16) * 32 + quad * 8;

    #pragma unroll 4
    for (int kb = 0; kb < KB; ++kb) {
        const ushort* ak = a0 + (size_t)kb * (M * 32);
        const ushort* bk = bp + (size_t)kb * (Npad * 32);
        short8 af0 = *(const short8*)(ak);
        short8 af1 = *(const short8*)(ak + 16 * 32);
        short8 bf[2];
        #pragma unroll
        for (int t = 0; t < 2; ++t)
            bf[t] = *(const short8*)(bk + t * 16 * 32);
        #pragma unroll
        for (int t = 0; t < 2; ++t) {
            acc[0][t] = __builtin_amdgcn_mfma_f32_16x16x32_bf16(af0, bf[t], acc[0][t], 0, 0, 0);
            acc[1][t] = __builtin_amdgcn_mfma_f32_16x16x32_bf16(af1, bf[t], acc[1][t], 0, 0, 0);
        }
    }

    if (mode == 0) {
        #pragma unroll
        for (int a = 0; a < 2; ++a)
            #pragma unroll
            for (int r = 0; r < 4; ++r) {
                int m = m0 + a * 16 + quad * 4 + r;
                float bb = bias[m];
                #pragma unroll
                for (int t = 0; t < 2; ++t) {
                    int n = n0 + t * 16 + l16;
                    size_t o = ((size_t)b * NCn + m) * N + n;
                    Yf[o] = acc[a][t][r] + bb + resid[o];
                }
            }
    } else {  // mode 3: GELU -> t1T (bg, hw, c): float4 over r (m-contiguous)
        #pragma unroll
        for (int a = 0; a < 2; ++a) {
            const int mbase = m0 + a * 16 + quad * 4;     // 4-aligned
            float bb[4];
            #pragma unroll
            for (int r = 0; r < 4; ++r) bb[r] = bias[mbase + r];
            #pragma unroll
            for (int t = 0; t < 2; ++t) {
                int n = n0 + t * 16 + l16;
                float4 v;
                v.x = gelu_f(acc[a][t][0] + bb[0]);
                v.y = gelu_f(acc[a][t][1] + bb[1]);
                v.z = gelu_f(acc[a][t][2] + bb[2]);
                v.w = gelu_f(acc[a][t][3] + bb[3]);
                *(float4*)&Yf[(((size_t)b << 10) + n) * 64 + mbase] = v;
            }
        }
    }
}

// ---------------------------------------------------------------------------
// Fused Q + K + V projections — R12 structure (shared-B fused KV + K-outer
// layouts). R13: Q pre-scaled by CEXP. R15/R16: V tiled (b,h,kb,d,32) with
// n<960 guard. R17: unroll 2 both paths.
// grid (4, 12, 16); z<8: Q path batch z; z>=8: fused KV path batch z-8.
// [R22: R10 configuration restored verbatim — best measured at 249.4 µs.
//  R19 32n-split (+7), R20/R21 Q-extraction merge (+5) both regressed:
//  the Q-planes ARE the KV launch's co-resident TLP.]
// ---------------------------------------------------------------------------
__global__ __launch_bounds__(256) void k_gemm_qkv(
    const ushort* __restrict__ qwb, const ushort* __restrict__ kwb,
    const ushort* __restrict__ vwb,
    const ushort* __restrict__ qXT, const ushort* __restrict__ smpT,
    const float* __restrict__ q_b, const float* __restrict__ k_b,
    const float* __restrict__ v_b,
    ushort* __restrict__ qTb, ushort* __restrict__ kTb, ushort* __restrict__ vTb)
{
    const int nb = blockIdx.x, mb = blockIdx.y;
    const int w = threadIdx.x >> 6, lane = threadIdx.x & 63;
    const int l16 = lane & 15, quad = lane >> 4;
    const int m0 = mb * 32;
    const int n0 = nb * 256 + w * 64;
    floatx4 zero = {0.0f, 0.0f, 0.0f, 0.0f};

    if (blockIdx.z < Bn) {
        const int b = blockIdx.z;
        floatx4 acc[2][4] = {{zero, zero, zero, zero}, {zero, zero, zero, zero}};
        // (kb, m, 32) weights; (b, kb, n, 32) activations — all 1KB/wave loads
        const ushort* a0 = qwb + (size_t)(m0 + l16) * 32 + quad * 8;
        const ushort* bp = qXT + ((size_t)b * KBq * NQn + n0 + l16) * 32 + quad * 8;

        #pragma unroll 2
        for (int kb = 0; kb < KBq; ++kb) {
            const ushort* ak = a0 + (size_t)kb * (NCn * 32);
            const ushort* bk = bp + (size_t)kb * (NQn * 32);
            short8 af0 = *(const short8*)(ak);
            short8 af1 = *(const short8*)(ak + 16 * 32);
            short8 bf[4];
            #pragma unroll
            for (int t = 0; t < 4; ++t)
                bf[t] = *(const short8*)(bk + t * 16 * 32);
            #pragma unroll
            for (int t = 0; t < 4; ++t) {
                acc[0][t] = __builtin_amdgcn_mfma_f32_16x16x32_bf16(af0, bf[t], acc[0][t], 0, 0, 0);
                acc[1][t] = __builtin_amdgcn_mfma_f32_16x16x32_bf16(af1, bf[t], acc[1][t], 0, 0, 0);
            }
        }
        // head = mb; d = a*16 + quad*4 + r  ->  r is contiguous: ushort4 pack
        #pragma unroll
        for (int a = 0; a < 2; ++a) {
            #pragma unroll
            for (int t2 = 0; t2 < 4; ++t2) {
                int n = n0 + t2 * 16 + l16;   // always < 1024
                ushort4 pk;
                pk.x = f2bf((acc[a][t2][0] + q_b[m0 + a * 16 + quad * 4 + 0]) * CEXP);
                pk.y = f2bf((acc[a][t2][1] + q_b[m0 + a * 16 + quad * 4 + 1]) * CEXP);
                pk.z = f2bf((acc[a][t2][2] + q_b[m0 + a * 16 + quad * 4 + 2]) * CEXP);
                pk.w = f2bf((acc[a][t2][3] + q_b[m0 + a * 16 + quad * 4 + 3]) * CEXP);
                *(ushort4*)&qTb[((size_t)(b * HEADSn + mb) * NQn + n) * 32 +
                                a * 16 + quad * 4] = pk;
            }
        }
    } else {
        const int b = blockIdx.z - Bn;
        floatx4 acck[2][4] = {{zero, zero, zero, zero}, {zero, zero, zero, zero}};
        floatx4 accv[2][4] = {{zero, zero, zero, zero}, {zero, zero, zero, zero}};
        const ushort* ak0 = kwb + (size_t)(m0 + l16) * 32 + quad * 8;
        const ushort* av0 = vwb + (size_t)(m0 + l16) * 32 + quad * 8;
        const ushort* bp  = smpT + ((size_t)b * KBq * NQn + n0 + l16) * 32 + quad * 8;

        #pragma unroll 2
        for (int kb = 0; kb < KBq; ++kb) {
            const ushort* ak = ak0 + (size_t)kb * (NCn * 32);
            const ushort* av = av0 + (size_t)kb * (NCn * 32);
            const ushort* bk = bp + (size_t)kb * (NQn * 32);
            short8 afk0 = *(const short8*)(ak);
            short8 afk1 = *(const short8*)(ak + 16 * 32);
            short8 afv0 = *(const short8*)(av);
            short8 afv1 = *(const short8*)(av + 16 * 32);
            short8 bf[4];
            #pragma unroll
            for (int t = 0; t < 4; ++t)
                bf[t] = *(const short8*)(bk + t * 16 * 32);
            #pragma unroll
            for (int t = 0; t < 4; ++t) {
                acck[0][t] = __builtin_amdgcn_mfma_f32_16x16x32_bf16(afk0, bf[t], acck[0][t], 0, 0, 0);
                acck[1][t] = __builtin_amdgcn_mfma_f32_16x16x32_bf16(afk1, bf[t], acck[1][t], 0, 0, 0);
                accv[0][t] = __builtin_amdgcn_mfma_f32_16x16x32_bf16(afv0, bf[t], accv[0][t], 0, 0, 0);
                accv[1][t] = __builtin_amdgcn_mfma_f32_16x16x32_bf16(afv1, bf[t], accv[1][t], 0, 0, 0);
            }
        }
        #pragma unroll
        for (int a = 0; a < 2; ++a) {
            #pragma unroll
            for (int t2 = 0; t2 < 4; ++t2) {
                int n = n0 + t2 * 16 + l16;
                if (n < NKVn) {
                    ushort4 pk;
                    pk.x = f2bf(acck[a][t2][0] + k_b[m0 + a * 16 + quad * 4 + 0]);
                    pk.y = f2bf(acck[a][t2][1] + k_b[m0 + a * 16 + quad * 4 + 1]);
                    pk.z = f2bf(acck[a][t2][2] + k_b[m0 + a * 16 + quad * 4 + 2]);
                    pk.w = f2bf(acck[a][t2][3] + k_b[m0 + a * 16 + quad * 4 + 3]);
                    *(ushort4*)&kTb[((size_t)(b * HEADSn + mb) * NKVn + n) * 32 +
                                    a * 16 + quad * 4] = pk;
                }
            }
        }
        // V epilogue — R15 tiled layout (b, h=mb, n>>5, d, n&31); R16: n<960 guard
        #pragma unroll
        for (int a = 0; a < 2; ++a)
            #pragma unroll
            for (int r = 0; r < 4; ++r) {
                int d = a * 16 + quad * 4 + r;
                float bv = v_b[m0 + d];
                #pragma unroll
                for (int t2 = 0; t2 < 4; ++t2) {
                    int n = n0 + t2 * 16 + l16;   // 0..1023!
                    if (n < VKB * 32)
                        vTb[(((size_t)(b * HEADSn + mb) * VKB + (n >> 5)) * 32 + d) * 32 +
                            (n & 31)] = (n < NKVn) ? f2bf(accv[a][t2][r] + bv) : (ushort)0;
                }
            }
    }
}

// ---------------------------------------------------------------------------
// Flash attention, bf16 MFMA, 32 queries/wave, K/V register prefetch.
// 768 blocks 1-D: b = id%8, j = id/8: h = j%12, mt = j/12.
// R13: raw v_exp (scores pre-scaled in Q), XOR-swizzled P tile (16 KB).
// R15: V in (b,h,kb,d,32) tiles -> vf loads 1KB-contiguous; setprio on MFMA
// clusters (4 independent waves/block, no barriers — measured +4-7% regime).
// ---------------------------------------------------------------------------
__global__ __launch_bounds__(256) void k_attn_mfma(
    const ushort* __restrict__ qT, const ushort* __restrict__ kT,
    const ushort* __restrict__ vb, ushort* __restrict__ aoutT)
{
    __shared__ __align__(16) ushort p_lds[4 * 2 * 16 * 64];   // 16 KB
    const int b = blockIdx.x & 7;
    const int j = blockIdx.x >> 3;          // 0..95
    const int h = j % HEADSn, mt = j / HEADSn;   // mt 0..7
    const int bh = b * HEADSn + h;
    const int tid = threadIdx.x;
    const int w = tid >> 6, lane = tid & 63;
    const int l16 = lane & 15, quad = lane >> 4;

    ushort* p_w[2] = { p_lds + (w * 2 + 0) * (16 * 64),
                       p_lds + (w * 2 + 1) * (16 * 64) };

    const int q0 = mt * 128 + w * 32;
    short8 qf[2];
    qf[0] = *(const short8*)(qT + (size_t)((bh * NQn + q0 + l16) * 32 + quad * 8));
    qf[1] = *(const short8*)(qT + (size_t)((bh * NQn + q0 + 16 + l16) * 32 + quad * 8));

    const ushort* kbase = kT + (size_t)bh * NKVn * 32;
    const ushort* vbase = vb + (size_t)bh * (VKB * 1024);   // 32d x 32k tiles

    floatx4 zero = {0.0f, 0.0f, 0.0f, 0.0f};
    floatx4 oacc[2][2] = {{zero, zero}, {zero, zero}};
    float lrun[2][4] = {};

    short8 kf[4];
    #pragma unroll
    for (int t = 0; t < 4; ++t)
        kf[t] = *(const short8*)(kbase + (size_t)((t * 16 + l16) * 32 + quad * 8));

    for (int nc = 0; nc < 15; ++nc) {
        const int n0 = nc * 64;
        short8 vf[2][2];
        #pragma unroll
        for (int kc = 0; kc < 2; ++kc)
            #pragma unroll
            for (int nt2 = 0; nt2 < 2; ++nt2)
                vf[kc][nt2] = *(const short8*)(vbase +
                    (size_t)(((nc * 2 + kc) * 32 + nt2 * 16 + l16) * 32 + quad * 8));

        floatx4 sf[2][4];
        __builtin_amdgcn_s_setprio(1);
        #pragma unroll
        for (int a = 0; a < 2; ++a)
            #pragma unroll
            for (int t = 0; t < 4; ++t)
                sf[a][t] = __builtin_amdgcn_mfma_f32_16x16x32_bf16(qf[a], kf[t], zero, 0, 0, 0);
        __builtin_amdgcn_s_setprio(0);

        if (nc < 14) {
            #pragma unroll
            for (int t = 0; t < 4; ++t)
                kf[t] = *(const short8*)(kbase +
                    (size_t)((n0 + 64 + t * 16 + l16) * 32 + quad * 8));
        }

        if (n0 + 64 <= NKVn) {
            #pragma unroll
            for (int a = 0; a < 2; ++a)
                #pragma unroll
                for (int t = 0; t < 4; ++t)
                    #pragma unroll
                    for (int r = 0; r < 4; ++r) {
                        float p = __builtin_amdgcn_exp2f(sf[a][t][r]);
                        lrun[a][r] += p;
                        p_w[a][pidx(quad * 4 + r, t * 16 + l16)] = f2bf_fast(p);
                    }
        } else {
            const int limit = NKVn - n0;
            #pragma unroll
            for (int a = 0; a < 2; ++a)
                #pragma unroll
                for (int t = 0; t < 4; ++t) {
                    const int col = t * 16 + l16;
                    #pragma unroll
                    for (int r = 0; r < 4; ++r) {
                        float p = (col < limit) ? __builtin_amdgcn_exp2f(sf[a][t][r]) : 0.0f;
                        lrun[a][r] += p;
                        p_w[a][pidx(quad * 4 + r, col)] = f2bf_fast(p);
                    }
                }
        }

        __builtin_amdgcn_s_setprio(1);
        #pragma unroll
        for (int a = 0; a < 2; ++a)
            #pragma unroll
            for (int kc = 0; kc < 2; ++kc) {
                const short8 pf = *(const short8*)(p_w[a] + pidx(l16, kc * 32 + quad * 8));
                #pragma unroll
                for (int nt2 = 0; nt2 < 2; ++nt2)
                    oacc[a][nt2] = __builtin_amdgcn_mfma_f32_16x16x32_bf16(
                        pf, vf[kc][nt2], oacc[a][nt2], 0, 0, 0);
            }
        __builtin_amdgcn_s_setprio(0);
    }

    #pragma unroll
    for (int a = 0; a < 2; ++a)
        #pragma unroll
        for (int r = 0; r < 4; ++r) {
            float l = lrun[a][r];
            l += __shfl_xor(l, 1, 64);
            l += __shfl_xor(l, 2, 64);
            l += __shfl_xor(l, 4, 64);
            l += __shfl_xor(l, 8, 64);
            lrun[a][r] = 1.0f / l;
        }

    #pragma unroll
    for (int a = 0; a < 2; ++a)
        #pragma unroll
        for (int nt2 = 0; nt2 < 2; ++nt2)
            #pragma unroll
            for (int r = 0; r < 4; ++r) {
                int m = q0 + a * 16 + quad * 4 + r;
                aoutT[((size_t)(b * HEADSn + h) * NQn + m) * 32 + nt2 * 16 + l16] =
                    f2bf(oacc[a][nt2][r] * lrun[a][r]);
            }
}

// ---------------------------------------------------------------------------
extern "C" void kernel_launch(void* const* d_in, const int* in_sizes, int n_in,
                              void* d_out, int out_size, void* d_ws, size_t ws_size,
                              hipStream_t stream) {
    const float* query = (const float*)d_in[0];
    const float* xr1   = (const float*)d_in[1];
    const float* xr2   = (const float*)d_in[2];
    const float* xx1   = (const float*)d_in[3];
    const float* xx2   = (const float*)d_in[4];
    const float* w1    = (const float*)d_in[5];
    const float* b1    = (const float*)d_in[6];
    const float* w2    = (const float*)d_in[7];
    const float* b2    = (const float*)d_in[8];
    const float* w3    = (const float*)d_in[9];
    const float* q_w   = (const float*)d_in[10];
    const float* q_b   = (const float*)d_in[11];
    const float* k_w   = (const float*)d_in[12];
    const float* k_b   = (const float*)d_in[13];
    const float* v_w   = (const float*)d_in[14];
    const float* v_b   = (const float*)d_in[15];
    const float* o_w   = (const float*)d_in[16];
    const float* o_b   = (const float*)d_in[17];
    float* out = (float*)d_out;

    // ---- workspace layout (float units), with liveness overlap ----
    float* ws = (float*)d_ws;
    ushort* dataT = (ushort*)ws;                   // 48*8*1024*32 u = 6,291,456 f
    ushort* qTb   = (ushort*)(ws + 1572864);       // 8*12*1024*32 u (dataT dead by qkv) ✓
    ushort* aoutT = (ushort*)(ws + 3145728);       // 8*12*1024*32 u
    float*  t1T   = ws + 6291456;                  // 48*1024*64 fp32 = 3,145,728 f
    ushort* kTb   = (ushort*)(ws + 6291456);       // overlays t1T (dead after k_offsets) ✓
    ushort* vTb   = (ushort*)(ws + 7673856);       // 8*12*30*1024 u (same 2,949,120 u)
    float*  posb  = ws + 9437184;                  // 21,600 f (gap before smpT)
    ushort* smpT  = (ushort*)(ws + 9458816);       // 8*12*1024*32 u = 1,572,864 f
    ushort* wb    = (ushort*)(ws + 11031680);      // 606,208 u
    ushort* w1b = wb;
    ushort* qwb = wb + 16384;
    ushort* kwb = wb + 163840;
    ushort* vwb = wb + 311296;
    ushort* owb = wb + 458752;
    ushort* qXT2 = wb + 606208;                    // 8*12*1024*32 u (own slot: k_prep
                                                   //  writes it concurrently with dataT)

    k_prep<<<dim3(1024), 256, 0, stream>>>(xr1, xr2, xx1, xx2, query,
                                           w1, q_w, k_w, v_w, o_w,
                                           dataT, qXT2, wb);
    k_gemm<<<dim3(8, 2, 48), 256, 0, stream>>>(w1b, dataT, b1, nullptr,
                                               t1T, 256, NQn, NQn, 3);
    k_offsets<<<dim3(2700), 256, 0, stream>>>(t1T, w2, b2, w3, posb);
    k_sample<<<dim3(192, 4), 256, 0, stream>>>(xr1, xr2, xx1, xx2, posb, smpT);
    k_gemm_qkv<<<dim3(4, 12, 16), 256, 0, stream>>>(qwb, kwb, vwb, qXT2, smpT,
                                                    q_b, k_b, v_b, qTb, kTb, vTb);
    k_attn_mfma<<<dim3(768), 256, 0, stream>>>(qTb, kTb, vTb, aoutT);
    k_gemm<<<dim3(8, 12, Bn), 256, 0, stream>>>(owb, aoutT, o_b, query,
                                                out, NCn, NQn, NQn, 0);
}